// Round 1
// baseline (361.181 us; speedup 1.0000x reference)
//
#include <hip/hip_runtime.h>
#include <math.h>

#define VOCAB 32000
#define DD 4096
#define HH 1024
#define BB 256
#define SS 256

typedef unsigned long long u64;

// ---------------------------------------------------------------- reduce ----
__device__ __forceinline__ float blockReduceSum(float v, float* lds) {
    #pragma unroll
    for (int o = 32; o; o >>= 1) v += __shfl_down(v, o);
    int lane = threadIdx.x & 63, w = threadIdx.x >> 6;
    __syncthreads();                  // protect lds from previous use
    if (lane == 0) lds[w] = v;
    __syncthreads();
    float tot = 0.f;
    #pragma unroll
    for (int i = 0; i < 4; ++i) tot += lds[i];   // blockDim.x == 256 always
    return tot;
}

// ------------------------------------------------------------------ pool ----
// grid (4, nB); block 256. Each block accumulates a 1024-col slice of one row.
__global__ void pool_kernel(const int* __restrict__ ids, const int* __restrict__ mask,
                            const float* __restrict__ embed, float* __restrict__ out) {
    __shared__ int s_ids[SS];
    __shared__ int wofs[4];
    int b = blockIdx.y, slice = blockIdx.x, t = threadIdx.x;
    int id = ids[b * SS + t];
    int m  = mask[b * SS + t];
    u64 bal = __ballot(m != 0);
    int lane = t & 63, w = t >> 6;
    if (lane == 0) wofs[w] = __popcll(bal);
    __syncthreads();
    int off = 0;
    #pragma unroll
    for (int i = 0; i < 4; ++i) if (i < w) off += wofs[i];
    int total = wofs[0] + wofs[1] + wofs[2] + wofs[3];
    int pos = off + __popcll(bal & ((1ull << lane) - 1ull));
    if (m) s_ids[pos] = id;           // stable compaction of active ids
    __syncthreads();

    float inv = 1.0f / ((float)total + 1e-9f);
    int col = (slice << 10) + (t << 2);
    const float* eb = embed + col;
    float ax = 0.f, ay = 0.f, az = 0.f, aw = 0.f;
    int j = 0;
    for (; j + 4 <= total; j += 4) {  // 4 independent float4 loads in flight
        const float4 r0 = *(const float4*)(eb + (size_t)s_ids[j + 0] * DD);
        const float4 r1 = *(const float4*)(eb + (size_t)s_ids[j + 1] * DD);
        const float4 r2 = *(const float4*)(eb + (size_t)s_ids[j + 2] * DD);
        const float4 r3 = *(const float4*)(eb + (size_t)s_ids[j + 3] * DD);
        ax += (r0.x + r1.x) + (r2.x + r3.x);
        ay += (r0.y + r1.y) + (r2.y + r3.y);
        az += (r0.z + r1.z) + (r2.z + r3.z);
        aw += (r0.w + r1.w) + (r2.w + r3.w);
    }
    for (; j < total; ++j) {
        const float4 r0 = *(const float4*)(eb + (size_t)s_ids[j] * DD);
        ax += r0.x; ay += r0.y; az += r0.z; aw += r0.w;
    }
    float4 res = make_float4(ax * inv, ay * inv, az * inv, aw * inv);
    *(float4*)(out + (size_t)b * DD + col) = res;
}

// ------------------------------------------------------------------- LN -----
__global__ void ln_kernel(float* __restrict__ x, const float* __restrict__ g,
                          const float* __restrict__ bb) {
    __shared__ float lds[4];
    int b = blockIdx.x, t = threadIdx.x;
    float* row = x + (size_t)b * DD;
    float4 v[4];
    float s = 0.f;
    #pragma unroll
    for (int i = 0; i < 4; ++i) {
        v[i] = *(const float4*)(row + (t << 2) + (i << 10));
        s += (v[i].x + v[i].y) + (v[i].z + v[i].w);
    }
    float mu = blockReduceSum(s, lds) * (1.0f / DD);
    float q = 0.f;
    #pragma unroll
    for (int i = 0; i < 4; ++i) {
        float dx = v[i].x - mu, dy = v[i].y - mu, dz = v[i].z - mu, dw = v[i].w - mu;
        q += (dx * dx + dy * dy) + (dz * dz + dw * dw);
    }
    float var = blockReduceSum(q, lds) * (1.0f / DD);
    float sc = 1.0f / sqrtf(var + 1e-5f);
    #pragma unroll
    for (int i = 0; i < 4; ++i) {
        int col = (t << 2) + (i << 10);
        float4 gg = *(const float4*)(g + col);
        float4 bv = *(const float4*)(bb + col);
        float4 o;
        o.x = (v[i].x - mu) * sc * gg.x + bv.x;
        o.y = (v[i].y - mu) * sc * gg.y + bv.y;
        o.z = (v[i].z - mu) * sc * gg.z + bv.z;
        o.w = (v[i].w - mu) * sc * gg.w + bv.w;
        *(float4*)(row + col) = o;
    }
}

// ------------------------------------------------------------------ GEMM ----
// Y[M,N] = act(X[M,K] @ W[N,K]^T + bias). Tile 32(M)x64(N), BK=32, 256 thr,
// 2x4 outputs/thread. fp32 (no fp32 MFMA on CDNA4; precision needed for topk).
template <bool RELU>
__global__ void __launch_bounds__(256) gemm_kernel(
        const float* __restrict__ X, const float* __restrict__ Wt,
        const float* __restrict__ bias, float* __restrict__ Y,
        int M, int N, int K) {
    constexpr int BM = 32, BN = 64, BK = 32;
    __shared__ float sX[BK][BM + 1];
    __shared__ float sW[BK][BN + 1];
    int tid = threadIdx.x;
    int tx = tid & 15, ty = tid >> 4;
    int m0 = blockIdx.y * BM, n0 = blockIdx.x * BN;
    int lr = tid >> 3;            // 0..31
    int lk = (tid & 7) << 2;      // 0,4,...,28
    float acc[2][4] = {};
    for (int k0 = 0; k0 < K; k0 += BK) {
        float4 xv  = *(const float4*)(X  + (size_t)(m0 + lr) * K + k0 + lk);
        float4 wv0 = *(const float4*)(Wt + (size_t)(n0 + lr) * K + k0 + lk);
        float4 wv1 = *(const float4*)(Wt + (size_t)(n0 + lr + 32) * K + k0 + lk);
        sX[lk + 0][lr] = xv.x;  sX[lk + 1][lr] = xv.y;
        sX[lk + 2][lr] = xv.z;  sX[lk + 3][lr] = xv.w;
        sW[lk + 0][lr] = wv0.x; sW[lk + 1][lr] = wv0.y;
        sW[lk + 2][lr] = wv0.z; sW[lk + 3][lr] = wv0.w;
        sW[lk + 0][lr + 32] = wv1.x; sW[lk + 1][lr + 32] = wv1.y;
        sW[lk + 2][lr + 32] = wv1.z; sW[lk + 3][lr + 32] = wv1.w;
        __syncthreads();
        #pragma unroll
        for (int kk = 0; kk < BK; ++kk) {
            float x0 = sX[kk][ty], x1 = sX[kk][ty + 16];
            float w0 = sW[kk][tx],      w1 = sW[kk][tx + 16];
            float w2 = sW[kk][tx + 32], w3 = sW[kk][tx + 48];
            acc[0][0] += x0 * w0; acc[0][1] += x0 * w1;
            acc[0][2] += x0 * w2; acc[0][3] += x0 * w3;
            acc[1][0] += x1 * w0; acc[1][1] += x1 * w1;
            acc[1][2] += x1 * w2; acc[1][3] += x1 * w3;
        }
        __syncthreads();
    }
    #pragma unroll
    for (int i = 0; i < 2; ++i) {
        int m = m0 + ty + i * 16;
        #pragma unroll
        for (int j = 0; j < 4; ++j) {
            int n = n0 + tx + j * 16;
            float v = acc[i][j] + bias[n];
            if (RELU) v = fmaxf(v, 0.f);
            Y[(size_t)m * N + n] = v;
        }
    }
}

// ------------------------------------------------------------------ GEMV ----
template <bool RELU>
__global__ void gemv_kernel(const float* __restrict__ x, const float* __restrict__ Wt,
                            const float* __restrict__ bias, float* __restrict__ y, int K) {
    __shared__ float lds[4];
    int n = blockIdx.x, t = threadIdx.x;
    const float* wr = Wt + (size_t)n * K;
    float s = 0.f;
    for (int k = t << 2; k < K; k += 1024) {
        float4 a = *(const float4*)(x + k);
        float4 w = *(const float4*)(wr + k);
        s += (a.x * w.x + a.y * w.y) + (a.z * w.z + a.w * w.w);
    }
    float tot = blockReduceSum(s, lds);
    if (t == 0) {
        tot += bias[n];
        y[n] = RELU ? fmaxf(tot, 0.f) : tot;
    }
}

// ---------------------------------------------------------------- scores ----
__global__ void scores_kernel(const float* __restrict__ q, const float* __restrict__ keys,
                              float* __restrict__ scores) {
    __shared__ float lds[4];
    int b = blockIdx.x, t = threadIdx.x;
    const float* kr = keys + (size_t)b * HH;
    float4 a = *(const float4*)(q + (t << 2));
    float4 w = *(const float4*)(kr + (t << 2));
    float s = (a.x * w.x + a.y * w.y) + (a.z * w.z + a.w * w.w);
    float tot = blockReduceSum(s, lds);
    if (t == 0) scores[b] = 1.0f / (1.0f + expf(-tot));   // f32 sigmoid, matches ref
}

// ------------------------------------------------------------------ topk ----
// Stable tie-break: max value, lowest index first (jax.lax.top_k semantics).
__global__ void topk_kernel(const float* __restrict__ scores, const int* __restrict__ kptr,
                            float* __restrict__ out) {
    __shared__ float ss[BB];
    __shared__ float rv[4];
    __shared__ int   ri[4];
    int t = threadIdx.x;
    ss[t] = scores[t];
    int k = kptr[0];
    if (k > BB) k = BB;
    __syncthreads();
    for (int i = 0; i < k; ++i) {
        float v = ss[t]; int vi = t;
        #pragma unroll
        for (int o = 32; o; o >>= 1) {
            float ov = __shfl_down(v, o);
            int   oi = __shfl_down(vi, o);
            if (ov > v || (ov == v && oi < vi)) { v = ov; vi = oi; }
        }
        int lane = t & 63, w = t >> 6;
        if (lane == 0) { rv[w] = v; ri[w] = vi; }
        __syncthreads();
        if (t == 0) {
            float bv = rv[0]; int bi = ri[0];
            #pragma unroll
            for (int j = 1; j < 4; ++j)
                if (rv[j] > bv || (rv[j] == bv && ri[j] < bi)) { bv = rv[j]; bi = ri[j]; }
            out[i]     = bv;
            out[k + i] = (float)bi;   // idx as float (d_out is float*)
            ss[bi] = -3.0e38f;
        }
        __syncthreads();
    }
}

// ---------------------------------------------------------------- launch ----
extern "C" void kernel_launch(void* const* d_in, const int* in_sizes, int n_in,
                              void* d_out, int out_size, void* d_ws, size_t ws_size,
                              hipStream_t stream) {
    const int*   input_ids  = (const int*)d_in[0];
    const int*   attn_mask  = (const int*)d_in[1];
    const int*   query_ids  = (const int*)d_in[2];
    const int*   query_mask = (const int*)d_in[3];
    const float* embed      = (const float*)d_in[4];
    const float* ln_g       = (const float*)d_in[5];
    const float* ln_b       = (const float*)d_in[6];
    const float* kW1        = (const float*)d_in[7];
    const float* kb1        = (const float*)d_in[8];
    const float* kW2        = (const float*)d_in[9];
    const float* kb2        = (const float*)d_in[10];
    const float* qW1        = (const float*)d_in[11];
    const float* qb1        = (const float*)d_in[12];
    const float* qW2        = (const float*)d_in[13];
    const float* qb2        = (const float*)d_in[14];
    const int*   kptr       = (const int*)d_in[15];

    float* ws   = (float*)d_ws;
    float* Xk   = ws;                          // 256*4096
    float* Xq   = Xk + (size_t)BB * DD;        // 4096
    float* H1k  = Xq + DD;                     // 256*1024
    float* H1q  = H1k + (size_t)BB * HH;       // 1024
    float* Keys = H1q + HH;                    // 256*1024
    float* Qv   = Keys + (size_t)BB * HH;      // 1024
    float* Sc   = Qv + HH;                     // 256

    pool_kernel<<<dim3(4, BB), 256, 0, stream>>>(input_ids, attn_mask, embed, Xk);
    pool_kernel<<<dim3(4, 1), 256, 0, stream>>>(query_ids, query_mask, embed, Xq);
    ln_kernel<<<BB, 256, 0, stream>>>(Xk, ln_g, ln_b);
    ln_kernel<<<1, 256, 0, stream>>>(Xq, ln_g, ln_b);
    gemm_kernel<true ><<<dim3(HH / 64, BB / 32), 256, 0, stream>>>(Xk, kW1, kb1, H1k, BB, HH, DD);
    gemv_kernel<true ><<<HH, 256, 0, stream>>>(Xq, qW1, qb1, H1q, DD);
    gemm_kernel<false><<<dim3(HH / 64, BB / 32), 256, 0, stream>>>(H1k, kW2, kb2, Keys, BB, HH, HH);
    gemv_kernel<false><<<HH, 256, 0, stream>>>(H1q, qW2, qb2, Qv, HH);
    scores_kernel<<<BB, 256, 0, stream>>>(Qv, Keys, Sc);
    topk_kernel<<<1, 256, 0, stream>>>(Sc, kptr, (float*)d_out);
}

// Round 2
// 214.767 us; speedup vs baseline: 1.6817x; 1.6817x over previous
//
#include <hip/hip_runtime.h>
#include <math.h>

#define VOCAB 32000
#define DD 4096
#define HH 1024
#define BB 256
#define SS 256

typedef unsigned long long u64;

// ---------------------------------------------------------------- reduce ----
__device__ __forceinline__ float blockReduceSum(float v, float* lds) {
    #pragma unroll
    for (int o = 32; o; o >>= 1) v += __shfl_down(v, o);
    int lane = threadIdx.x & 63, w = threadIdx.x >> 6;
    __syncthreads();
    if (lane == 0) lds[w] = v;
    __syncthreads();
    float tot = 0.f;
    #pragma unroll
    for (int i = 0; i < 4; ++i) tot += lds[i];
    return tot;
}

// ------------------------------------------------------------------ pool ----
// grid (4, 257); b==256 is the query row. Block accumulates a 1024-col slice.
__global__ void pool_kernel(const int* __restrict__ ids, const int* __restrict__ mask,
                            const int* __restrict__ qids, const int* __restrict__ qmask,
                            const float* __restrict__ embed, float* __restrict__ out) {
    __shared__ int s_ids[SS];
    __shared__ int wofs[4];
    int b = blockIdx.y, slice = blockIdx.x, t = threadIdx.x;
    const int* I = (b < BB) ? ids  + b * SS : qids;
    const int* M = (b < BB) ? mask + b * SS : qmask;
    int id = I[t];
    int m  = M[t];
    u64 bal = __ballot(m != 0);
    int lane = t & 63, w = t >> 6;
    if (lane == 0) wofs[w] = __popcll(bal);
    __syncthreads();
    int off = 0;
    #pragma unroll
    for (int i = 0; i < 4; ++i) if (i < w) off += wofs[i];
    int total = wofs[0] + wofs[1] + wofs[2] + wofs[3];
    int pos = off + __popcll(bal & ((1ull << lane) - 1ull));
    if (m) s_ids[pos] = id;           // stable compaction of active ids
    __syncthreads();

    float inv = 1.0f / ((float)total + 1e-9f);
    int col = (slice << 10) + (t << 2);
    const float* eb = embed + col;
    float ax = 0.f, ay = 0.f, az = 0.f, aw = 0.f;
    int j = 0;
    for (; j + 4 <= total; j += 4) {
        const float4 r0 = *(const float4*)(eb + (size_t)s_ids[j + 0] * DD);
        const float4 r1 = *(const float4*)(eb + (size_t)s_ids[j + 1] * DD);
        const float4 r2 = *(const float4*)(eb + (size_t)s_ids[j + 2] * DD);
        const float4 r3 = *(const float4*)(eb + (size_t)s_ids[j + 3] * DD);
        ax += (r0.x + r1.x) + (r2.x + r3.x);
        ay += (r0.y + r1.y) + (r2.y + r3.y);
        az += (r0.z + r1.z) + (r2.z + r3.z);
        aw += (r0.w + r1.w) + (r2.w + r3.w);
    }
    for (; j < total; ++j) {
        const float4 r0 = *(const float4*)(eb + (size_t)s_ids[j] * DD);
        ax += r0.x; ay += r0.y; az += r0.z; aw += r0.w;
    }
    float4 res = make_float4(ax * inv, ay * inv, az * inv, aw * inv);
    *(float4*)(out + (size_t)b * DD + col) = res;
}

// ------------------------------------------------------------------- LN -----
__global__ void ln_kernel(float* __restrict__ x, const float* __restrict__ g,
                          const float* __restrict__ bb) {
    __shared__ float lds[4];
    int b = blockIdx.x, t = threadIdx.x;
    float* row = x + (size_t)b * DD;
    float4 v[4];
    float s = 0.f;
    #pragma unroll
    for (int i = 0; i < 4; ++i) {
        v[i] = *(const float4*)(row + (t << 2) + (i << 10));
        s += (v[i].x + v[i].y) + (v[i].z + v[i].w);
    }
    float mu = blockReduceSum(s, lds) * (1.0f / DD);
    float q = 0.f;
    #pragma unroll
    for (int i = 0; i < 4; ++i) {
        float dx = v[i].x - mu, dy = v[i].y - mu, dz = v[i].z - mu, dw = v[i].w - mu;
        q += (dx * dx + dy * dy) + (dz * dz + dw * dw);
    }
    float var = blockReduceSum(q, lds) * (1.0f / DD);
    float sc = 1.0f / sqrtf(var + 1e-5f);
    #pragma unroll
    for (int i = 0; i < 4; ++i) {
        int col = (t << 2) + (i << 10);
        float4 gg = *(const float4*)(g + col);
        float4 bv = *(const float4*)(bb + col);
        float4 o;
        o.x = (v[i].x - mu) * sc * gg.x + bv.x;
        o.y = (v[i].y - mu) * sc * gg.y + bv.y;
        o.z = (v[i].z - mu) * sc * gg.z + bv.z;
        o.w = (v[i].w - mu) * sc * gg.w + bv.w;
        *(float4*)(row + col) = o;
    }
}

// -------------------------------------------------------------- gemm body ---
// Tile BM=32 x BN=64, BK=32, 256 threads, 2x4 out/thread (consecutive n quad).
// Writes partial (no bias) to Pout[m*N+n] for k-range [kBase, kBase+Kc).
// FUSE_A: A(m,k) = relu(A0[m*ldA+k] + A1[m*ldA+k] + prebias[k])
template <bool FUSE_A>
__device__ __forceinline__ void gemm_body(
        const float* __restrict__ A0, const float* __restrict__ A1,
        const float* __restrict__ prebias, const float* __restrict__ Wt,
        float* __restrict__ Pout, int N, int K, int ldA,
        int m0, int n0, int kBase, int Kc) {
    constexpr int BM = 32, BN = 64, BK = 32;
    __shared__ float sX[BK][BM + 2];   // stride 34 (even -> aligned float2)
    __shared__ float sW[BK][BN + 4];   // stride 68 (16B-aligned float4 rows)
    int tid = threadIdx.x;
    int tx = tid & 15, ty = tid >> 4;          // out: n quad tx*4, rows 2ty,2ty+1
    int lrA = tid >> 3, kA = (tid & 7) << 2;   // A stage: 32 rows x 32 k
    int nB = tid >> 2, kB = (tid & 3) << 2;    // B stage: 64 rows x 16 k (x2)
    float acc[2][4] = {};

    for (int k0 = 0; k0 < Kc; k0 += BK) {
        int gk = kBase + k0;
        float4 av;
        {
            size_t ao = (size_t)(m0 + lrA) * ldA + gk + kA;
            if (FUSE_A) {
                float4 p0 = *(const float4*)(A0 + ao);
                float4 p1 = *(const float4*)(A1 + ao);
                float4 pb = *(const float4*)(prebias + gk + kA);
                av.x = fmaxf(p0.x + p1.x + pb.x, 0.f);
                av.y = fmaxf(p0.y + p1.y + pb.y, 0.f);
                av.z = fmaxf(p0.z + p1.z + pb.z, 0.f);
                av.w = fmaxf(p0.w + p1.w + pb.w, 0.f);
            } else {
                av = *(const float4*)(A0 + ao);
            }
        }
        float4 wv0 = *(const float4*)(Wt + (size_t)(n0 + nB) * K + gk + kB);
        float4 wv1 = *(const float4*)(Wt + (size_t)(n0 + nB) * K + gk + kB + 16);
        sX[kA + 0][lrA] = av.x; sX[kA + 1][lrA] = av.y;
        sX[kA + 2][lrA] = av.z; sX[kA + 3][lrA] = av.w;
        sW[kB + 0][nB] = wv0.x; sW[kB + 1][nB] = wv0.y;
        sW[kB + 2][nB] = wv0.z; sW[kB + 3][nB] = wv0.w;
        sW[kB + 16][nB] = wv1.x; sW[kB + 17][nB] = wv1.y;
        sW[kB + 18][nB] = wv1.z; sW[kB + 19][nB] = wv1.w;
        __syncthreads();
        #pragma unroll
        for (int kk = 0; kk < BK; ++kk) {
            float2 x01 = *(const float2*)&sX[kk][ty << 1];
            float4 w = *(const float4*)&sW[kk][tx << 2];
            acc[0][0] += x01.x * w.x; acc[0][1] += x01.x * w.y;
            acc[0][2] += x01.x * w.z; acc[0][3] += x01.x * w.w;
            acc[1][0] += x01.y * w.x; acc[1][1] += x01.y * w.y;
            acc[1][2] += x01.y * w.z; acc[1][3] += x01.y * w.w;
        }
        __syncthreads();
    }
    #pragma unroll
    for (int i = 0; i < 2; ++i) {
        int m = m0 + (ty << 1) + i;
        *(float4*)(Pout + (size_t)m * N + n0 + (tx << 2)) =
            make_float4(acc[i][0], acc[i][1], acc[i][2], acc[i][3]);
    }
}

// -------------------------------------------------------------- gemv body ---
template <bool RELU>
__device__ __forceinline__ void gemv_body(
        const float* __restrict__ x, const float* __restrict__ Wt,
        const float* __restrict__ bias, float* __restrict__ y, int K, int n) {
    __shared__ float lds[4];
    int t = threadIdx.x;
    const float* wr = Wt + (size_t)n * K;
    float s = 0.f;
    for (int k = t << 2; k < K; k += 1024) {
        float4 a = *(const float4*)(x + k);
        float4 w = *(const float4*)(wr + k);
        s += (a.x * w.x + a.y * w.y) + (a.z * w.z + a.w * w.w);
    }
    float tot = blockReduceSum(s, lds);
    if (t == 0) {
        tot += bias[n];
        y[n] = RELU ? fmaxf(tot, 0.f) : tot;
    }
}

// --------------------------------------------------------------- layer 1 ----
// blocks [0,256): keys GEMM X[257? uses rows 0..255] @ kW1^T, split-K=2 -> P1
// blocks [256,1280): query GEMV row 256 of X @ qW1^T + qb1, relu -> H1q
__global__ void __launch_bounds__(256) layer1_kernel(
        const float* __restrict__ X, const float* __restrict__ kW1,
        float* __restrict__ P1,
        const float* __restrict__ qW1, const float* __restrict__ qb1,
        float* __restrict__ H1q) {
    int bid = blockIdx.x;
    if (bid < 256) {
        int bx = bid & 15, by = (bid >> 4) & 7, bz = bid >> 7;
        gemm_body<false>(X, nullptr, nullptr, kW1,
                         P1 + (size_t)bz * BB * HH, HH, DD, DD,
                         by * 32, bx * 64, bz * 2048, 2048);
    } else {
        gemv_body<true>(X + (size_t)BB * DD, qW1, qb1, H1q, DD, bid - 256);
    }
}

// --------------------------------------------------------------- layer 2 ----
// blocks [0,256): keys GEMM relu(P1a+P1b+kb1) @ kW2^T, split-K=2 -> P2
// blocks [256,1280): query GEMV H1q @ qW2^T + qb2 -> Qv
__global__ void __launch_bounds__(256) layer2_kernel(
        const float* __restrict__ P1, const float* __restrict__ kb1,
        const float* __restrict__ kW2, float* __restrict__ P2,
        const float* __restrict__ H1q, const float* __restrict__ qW2,
        const float* __restrict__ qb2, float* __restrict__ Qv) {
    int bid = blockIdx.x;
    if (bid < 256) {
        int bx = bid & 15, by = (bid >> 4) & 7, bz = bid >> 7;
        gemm_body<true>(P1, P1 + (size_t)BB * HH, kb1, kW2,
                        P2 + (size_t)bz * BB * HH, HH, HH, HH,
                        by * 32, bx * 64, bz * 512, 512);
    } else {
        gemv_body<false>(H1q, qW2, qb2, Qv, HH, bid - 256);
    }
}

// ---------------------------------------------------------------- scores ----
// Sc[b] = sigmoid( sum_h (P2a[b][h]+P2b[b][h]+kb2[h]) * Qv[h] )
__global__ void scores_kernel(const float* __restrict__ P2, const float* __restrict__ kb2,
                              const float* __restrict__ Qv, float* __restrict__ Sc) {
    __shared__ float lds[4];
    int b = blockIdx.x, t = threadIdx.x;
    const float* pa = P2 + (size_t)b * HH;
    const float* pb = pa + (size_t)BB * HH;
    int h = t << 2;
    float4 a = *(const float4*)(pa + h);
    float4 c = *(const float4*)(pb + h);
    float4 bv = *(const float4*)(kb2 + h);
    float4 q = *(const float4*)(Qv + h);
    float s = (a.x + c.x + bv.x) * q.x + (a.y + c.y + bv.y) * q.y
            + (a.z + c.z + bv.z) * q.z + (a.w + c.w + bv.w) * q.w;
    float tot = blockReduceSum(s, lds);
    if (t == 0) Sc[b] = 1.0f / (1.0f + expf(-tot));
}

// ------------------------------------------------------------------ topk ----
__global__ void topk_kernel(const float* __restrict__ scores, const int* __restrict__ kptr,
                            float* __restrict__ out) {
    __shared__ float ss[BB];
    __shared__ float rv[4];
    __shared__ int   ri[4];
    int t = threadIdx.x;
    ss[t] = scores[t];
    int k = kptr[0];
    if (k > BB) k = BB;
    __syncthreads();
    for (int i = 0; i < k; ++i) {
        float v = ss[t]; int vi = t;
        #pragma unroll
        for (int o = 32; o; o >>= 1) {
            float ov = __shfl_down(v, o);
            int   oi = __shfl_down(vi, o);
            if (ov > v || (ov == v && oi < vi)) { v = ov; vi = oi; }
        }
        int lane = t & 63, w = t >> 6;
        if (lane == 0) { rv[w] = v; ri[w] = vi; }
        __syncthreads();
        if (t == 0) {
            float bv = rv[0]; int bi = ri[0];
            #pragma unroll
            for (int j = 1; j < 4; ++j)
                if (rv[j] > bv || (rv[j] == bv && ri[j] < bi)) { bv = rv[j]; bi = ri[j]; }
            out[i]     = bv;
            out[k + i] = (float)bi;
            ss[bi] = -3.0e38f;
        }
        __syncthreads();
    }
}

// ---------------------------------------------------------------- launch ----
extern "C" void kernel_launch(void* const* d_in, const int* in_sizes, int n_in,
                              void* d_out, int out_size, void* d_ws, size_t ws_size,
                              hipStream_t stream) {
    const int*   input_ids  = (const int*)d_in[0];
    const int*   attn_mask  = (const int*)d_in[1];
    const int*   query_ids  = (const int*)d_in[2];
    const int*   query_mask = (const int*)d_in[3];
    const float* embed      = (const float*)d_in[4];
    const float* ln_g       = (const float*)d_in[5];
    const float* ln_b       = (const float*)d_in[6];
    const float* kW1        = (const float*)d_in[7];
    const float* kb1        = (const float*)d_in[8];
    const float* kW2        = (const float*)d_in[9];
    const float* kb2        = (const float*)d_in[10];
    const float* qW1        = (const float*)d_in[11];
    const float* qb1        = (const float*)d_in[12];
    const float* qW2        = (const float*)d_in[13];
    const float* qb2        = (const float*)d_in[14];
    const int*   kptr       = (const int*)d_in[15];

    float* ws   = (float*)d_ws;
    float* X    = ws;                            // 257*4096 (row 256 = query)
    float* P1   = X  + (size_t)(BB + 1) * DD;    // 2*256*1024
    float* H1q  = P1 + (size_t)2 * BB * HH;      // 1024
    float* P2   = H1q + HH;                      // 2*256*1024
    float* Qv   = P2 + (size_t)2 * BB * HH;      // 1024
    float* Sc   = Qv + HH;                       // 256

    pool_kernel<<<dim3(4, BB + 1), 256, 0, stream>>>(input_ids, attn_mask,
                                                     query_ids, query_mask, embed, X);
    ln_kernel<<<BB + 1, 256, 0, stream>>>(X, ln_g, ln_b);
    layer1_kernel<<<1280, 256, 0, stream>>>(X, kW1, P1, qW1, qb1, H1q);
    layer2_kernel<<<1280, 256, 0, stream>>>(P1, kb1, kW2, P2, H1q, qW2, qb2, Qv);
    scores_kernel<<<BB, 256, 0, stream>>>(P2, kb2, Qv, Sc);
    topk_kernel<<<1, 256, 0, stream>>>(Sc, kptr, (float*)d_out);
}

// Round 3
// 200.681 us; speedup vs baseline: 1.7998x; 1.0702x over previous
//
#include <hip/hip_runtime.h>
#include <math.h>

#define VOCAB 32000
#define DD 4096
#define HH 1024
#define BB 256
#define SS 256

typedef unsigned long long u64;

// ------------------------------------------------------------- reductions ---
__device__ __forceinline__ float blockReduce256(float v, float* lds4) {
    #pragma unroll
    for (int o = 32; o; o >>= 1) v += __shfl_down(v, o);
    int lane = threadIdx.x & 63, w = threadIdx.x >> 6;
    __syncthreads();
    if (lane == 0) lds4[w] = v;
    __syncthreads();
    float tot = 0.f;
    #pragma unroll
    for (int i = 0; i < 4; ++i) tot += lds4[i];
    return tot;
}

__device__ __forceinline__ float blockReduce1024(float v, float* lds16) {
    #pragma unroll
    for (int o = 32; o; o >>= 1) v += __shfl_down(v, o);
    int lane = threadIdx.x & 63, w = threadIdx.x >> 6;
    __syncthreads();
    if (lane == 0) lds16[w] = v;
    __syncthreads();
    float tot = 0.f;
    #pragma unroll
    for (int i = 0; i < 16; ++i) tot += lds16[i];
    return tot;
}

// --------------------------------------------------------------- pool+LN ----
// grid 257, block 1024. Block b pools its full 4096-col row then LayerNorms.
__global__ void __launch_bounds__(1024) pool_ln_kernel(
        const int* __restrict__ ids, const int* __restrict__ mask,
        const int* __restrict__ qids, const int* __restrict__ qmask,
        const float* __restrict__ embed, const float* __restrict__ ln_g,
        const float* __restrict__ ln_b, float* __restrict__ out) {
    __shared__ int s_ids[SS];
    __shared__ int wofs[4];
    __shared__ float red[16];
    int b = blockIdx.x, t = threadIdx.x;
    const int* I = (b < BB) ? ids  + b * SS : qids;
    const int* M = (b < BB) ? mask + b * SS : qmask;
    int id = 0, m = 0;
    if (t < SS) { id = I[t]; m = M[t]; }
    u64 bal = __ballot(t < SS && m != 0);
    int lane = t & 63, w = t >> 6;
    if (t < SS && lane == 0) wofs[w] = __popcll(bal);
    __syncthreads();
    int total = wofs[0] + wofs[1] + wofs[2] + wofs[3];
    if (t < SS && m) {
        int off = 0;
        #pragma unroll
        for (int i = 0; i < 4; ++i) if (i < w) off += wofs[i];
        int pos = off + __popcll(bal & ((1ull << lane) - 1ull));
        s_ids[pos] = id;              // stable compaction of active ids
    }
    __syncthreads();

    float inv = 1.0f / ((float)total + 1e-9f);
    int col = t << 2;
    const float* eb = embed + col;
    float ax = 0.f, ay = 0.f, az = 0.f, aw = 0.f;
    int j = 0;
    for (; j + 4 <= total; j += 4) {  // 4 independent 16B loads in flight
        const float4 r0 = *(const float4*)(eb + (size_t)s_ids[j + 0] * DD);
        const float4 r1 = *(const float4*)(eb + (size_t)s_ids[j + 1] * DD);
        const float4 r2 = *(const float4*)(eb + (size_t)s_ids[j + 2] * DD);
        const float4 r3 = *(const float4*)(eb + (size_t)s_ids[j + 3] * DD);
        ax += (r0.x + r1.x) + (r2.x + r3.x);
        ay += (r0.y + r1.y) + (r2.y + r3.y);
        az += (r0.z + r1.z) + (r2.z + r3.z);
        aw += (r0.w + r1.w) + (r2.w + r3.w);
    }
    for (; j < total; ++j) {
        const float4 r0 = *(const float4*)(eb + (size_t)s_ids[j] * DD);
        ax += r0.x; ay += r0.y; az += r0.z; aw += r0.w;
    }
    float4 p = make_float4(ax * inv, ay * inv, az * inv, aw * inv);

    // LayerNorm over the 4096-col row held by this block
    float s = (p.x + p.y) + (p.z + p.w);
    float mu = blockReduce1024(s, red) * (1.0f / DD);
    float dx = p.x - mu, dy = p.y - mu, dz = p.z - mu, dw = p.w - mu;
    float q = (dx * dx + dy * dy) + (dz * dz + dw * dw);
    float var = blockReduce1024(q, red) * (1.0f / DD);
    float sc = 1.0f / sqrtf(var + 1e-5f);
    float4 gg = *(const float4*)(ln_g + col);
    float4 bv = *(const float4*)(ln_b + col);
    float4 o;
    o.x = dx * sc * gg.x + bv.x;
    o.y = dy * sc * gg.y + bv.y;
    o.z = dz * sc * gg.z + bv.z;
    o.w = dw * sc * gg.w + bv.w;
    *(float4*)(out + (size_t)b * DD + col) = o;
}

// -------------------------------------------------------------- gemm body ---
// Tile BM=64 x BN=64, BK=32, 256 threads, 4x4 out/thread. VALU-bound:
// per kk = 2x ds_read_b128 (24cy) vs 16 FMA (32cy).
// NPART==0: A(m,k) = A[m*ldA+k].
// NPART==4: A(m,k) = relu(sum_p A[m*ldA+k+p*partStride] + prebias[k]).
template <int NPART>
__device__ __forceinline__ void gemm_body(
        const float* __restrict__ A, const float* __restrict__ prebias,
        const float* __restrict__ Wt, float* __restrict__ Pout,
        int N, int K, int ldA, size_t partStride,
        int m0, int n0, int kBase, int Kc) {
    constexpr int BK = 32;
    __shared__ float sX[BK][68];   // [k][m], stride 68 floats = 17x16B (aligned)
    __shared__ float sW[BK][68];   // [k][n]
    int tid = threadIdx.x;
    int tx = tid & 15, ty = tid >> 4;       // out: n quad 4*tx, m quad 4*ty
    int lr = tid >> 3;                      // 0..31 (stage row)
    int kk4 = (tid & 7) << 2;               // 0,4,...,28 (stage k)
    float acc[4][4] = {};

    for (int k0 = 0; k0 < Kc; k0 += BK) {
        int gk = kBase + k0;
        float4 a0, a1;
        {
            size_t ao0 = (size_t)(m0 + lr) * ldA + gk + kk4;
            size_t ao1 = (size_t)(m0 + lr + 32) * ldA + gk + kk4;
            if (NPART == 4) {
                float4 pb = *(const float4*)(prebias + gk + kk4);
                float4 p00 = *(const float4*)(A + ao0);
                float4 p01 = *(const float4*)(A + ao0 + partStride);
                float4 p02 = *(const float4*)(A + ao0 + 2 * partStride);
                float4 p03 = *(const float4*)(A + ao0 + 3 * partStride);
                a0.x = fmaxf((p00.x + p01.x) + (p02.x + p03.x) + pb.x, 0.f);
                a0.y = fmaxf((p00.y + p01.y) + (p02.y + p03.y) + pb.y, 0.f);
                a0.z = fmaxf((p00.z + p01.z) + (p02.z + p03.z) + pb.z, 0.f);
                a0.w = fmaxf((p00.w + p01.w) + (p02.w + p03.w) + pb.w, 0.f);
                float4 p10 = *(const float4*)(A + ao1);
                float4 p11 = *(const float4*)(A + ao1 + partStride);
                float4 p12 = *(const float4*)(A + ao1 + 2 * partStride);
                float4 p13 = *(const float4*)(A + ao1 + 3 * partStride);
                a1.x = fmaxf((p10.x + p11.x) + (p12.x + p13.x) + pb.x, 0.f);
                a1.y = fmaxf((p10.y + p11.y) + (p12.y + p13.y) + pb.y, 0.f);
                a1.z = fmaxf((p10.z + p11.z) + (p12.z + p13.z) + pb.z, 0.f);
                a1.w = fmaxf((p10.w + p11.w) + (p12.w + p13.w) + pb.w, 0.f);
            } else {
                a0 = *(const float4*)(A + ao0);
                a1 = *(const float4*)(A + ao1);
            }
        }
        float4 w0 = *(const float4*)(Wt + (size_t)(n0 + lr) * K + gk + kk4);
        float4 w1 = *(const float4*)(Wt + (size_t)(n0 + lr + 32) * K + gk + kk4);
        sX[kk4 + 0][lr] = a0.x; sX[kk4 + 1][lr] = a0.y;
        sX[kk4 + 2][lr] = a0.z; sX[kk4 + 3][lr] = a0.w;
        sX[kk4 + 0][lr + 32] = a1.x; sX[kk4 + 1][lr + 32] = a1.y;
        sX[kk4 + 2][lr + 32] = a1.z; sX[kk4 + 3][lr + 32] = a1.w;
        sW[kk4 + 0][lr] = w0.x; sW[kk4 + 1][lr] = w0.y;
        sW[kk4 + 2][lr] = w0.z; sW[kk4 + 3][lr] = w0.w;
        sW[kk4 + 0][lr + 32] = w1.x; sW[kk4 + 1][lr + 32] = w1.y;
        sW[kk4 + 2][lr + 32] = w1.z; sW[kk4 + 3][lr + 32] = w1.w;
        __syncthreads();
        #pragma unroll
        for (int kk = 0; kk < BK; ++kk) {
            float4 x = *(const float4*)&sX[kk][ty << 2];
            float4 wv = *(const float4*)&sW[kk][tx << 2];
            acc[0][0] += x.x * wv.x; acc[0][1] += x.x * wv.y;
            acc[0][2] += x.x * wv.z; acc[0][3] += x.x * wv.w;
            acc[1][0] += x.y * wv.x; acc[1][1] += x.y * wv.y;
            acc[1][2] += x.y * wv.z; acc[1][3] += x.y * wv.w;
            acc[2][0] += x.z * wv.x; acc[2][1] += x.z * wv.y;
            acc[2][2] += x.z * wv.z; acc[2][3] += x.z * wv.w;
            acc[3][0] += x.w * wv.x; acc[3][1] += x.w * wv.y;
            acc[3][2] += x.w * wv.z; acc[3][3] += x.w * wv.w;
        }
        __syncthreads();
    }
    #pragma unroll
    for (int i = 0; i < 4; ++i) {
        int mrow = m0 + (ty << 2) + i;
        *(float4*)(Pout + (size_t)mrow * N + n0 + (tx << 2)) =
            make_float4(acc[i][0], acc[i][1], acc[i][2], acc[i][3]);
    }
}

// -------------------------------------------------------------- gemv body ---
template <bool RELU>
__device__ __forceinline__ void gemv_body(
        const float* __restrict__ x, const float* __restrict__ Wt,
        const float* __restrict__ bias, float* __restrict__ y, int K, int n) {
    __shared__ float lds4[4];
    int t = threadIdx.x;
    const float* wr = Wt + (size_t)n * K;
    float s = 0.f;
    for (int k = t << 2; k < K; k += 1024) {
        float4 a = *(const float4*)(x + k);
        float4 w = *(const float4*)(wr + k);
        s += (a.x * w.x + a.y * w.y) + (a.z * w.z + a.w * w.w);
    }
    float tot = blockReduce256(s, lds4);
    if (t == 0) {
        tot += bias[n];
        y[n] = RELU ? fmaxf(tot, 0.f) : tot;
    }
}

// --------------------------------------------------------------- layer 1 ----
__global__ void __launch_bounds__(256) layer1_kernel(
        const float* __restrict__ X, const float* __restrict__ kW1,
        float* __restrict__ P1,
        const float* __restrict__ qW1, const float* __restrict__ qb1,
        float* __restrict__ H1q) {
    int bid = blockIdx.x;
    if (bid < 256) {
        int bx = bid & 15, by = (bid >> 4) & 3, bz = bid >> 6;
        gemm_body<0>(X, nullptr, kW1, P1 + (size_t)bz * BB * HH,
                     HH, DD, DD, 0, by * 64, bx * 64, bz * 1024, 1024);
    } else {
        gemv_body<true>(X + (size_t)BB * DD, qW1, qb1, H1q, DD, bid - 256);
    }
}

// --------------------------------------------------------------- layer 2 ----
__global__ void __launch_bounds__(256) layer2_kernel(
        const float* __restrict__ P1, const float* __restrict__ kb1,
        const float* __restrict__ kW2, float* __restrict__ P2,
        const float* __restrict__ H1q, const float* __restrict__ qW2,
        const float* __restrict__ qb2, float* __restrict__ Qv) {
    int bid = blockIdx.x;
    if (bid < 256) {
        int bx = bid & 15, by = (bid >> 4) & 3, bz = bid >> 6;
        gemm_body<4>(P1, kb1, kW2, P2 + (size_t)bz * BB * HH,
                     HH, HH, HH, (size_t)BB * HH, by * 64, bx * 64, bz * 256, 256);
    } else {
        gemv_body<false>(H1q, qW2, qb2, Qv, HH, bid - 256);
    }
}

// ---------------------------------------------------------------- scores ----
// Sc[b] = sigmoid( sum_h (P2[0..3][b][h] + kb2[h]) * Qv[h] )
__global__ void scores_kernel(const float* __restrict__ P2, const float* __restrict__ kb2,
                              const float* __restrict__ Qv, float* __restrict__ Sc) {
    __shared__ float lds4[4];
    int b = blockIdx.x, t = threadIdx.x;
    size_t ps = (size_t)BB * HH;
    const float* pa = P2 + (size_t)b * HH;
    int h = t << 2;
    float4 p0 = *(const float4*)(pa + h);
    float4 p1 = *(const float4*)(pa + ps + h);
    float4 p2 = *(const float4*)(pa + 2 * ps + h);
    float4 p3 = *(const float4*)(pa + 3 * ps + h);
    float4 bv = *(const float4*)(kb2 + h);
    float4 q = *(const float4*)(Qv + h);
    float s = ((p0.x + p1.x) + (p2.x + p3.x) + bv.x) * q.x
            + ((p0.y + p1.y) + (p2.y + p3.y) + bv.y) * q.y
            + ((p0.z + p1.z) + (p2.z + p3.z) + bv.z) * q.z
            + ((p0.w + p1.w) + (p2.w + p3.w) + bv.w) * q.w;
    float tot = blockReduce256(s, lds4);
    if (t == 0) Sc[b] = 1.0f / (1.0f + expf(-tot));
}

// ------------------------------------------------------------------ topk ----
__global__ void topk_kernel(const float* __restrict__ scores, const int* __restrict__ kptr,
                            float* __restrict__ out) {
    __shared__ float ss[BB];
    __shared__ float rv[4];
    __shared__ int   ri[4];
    int t = threadIdx.x;
    ss[t] = scores[t];
    int k = kptr[0];
    if (k > BB) k = BB;
    __syncthreads();
    for (int i = 0; i < k; ++i) {
        float v = ss[t]; int vi = t;
        #pragma unroll
        for (int o = 32; o; o >>= 1) {
            float ov = __shfl_down(v, o);
            int   oi = __shfl_down(vi, o);
            if (ov > v || (ov == v && oi < vi)) { v = ov; vi = oi; }
        }
        int lane = t & 63, w = t >> 6;
        if (lane == 0) { rv[w] = v; ri[w] = vi; }
        __syncthreads();
        if (t == 0) {
            float bv = rv[0]; int bi = ri[0];
            #pragma unroll
            for (int j = 1; j < 4; ++j)
                if (rv[j] > bv || (rv[j] == bv && ri[j] < bi)) { bv = rv[j]; bi = ri[j]; }
            out[i]     = bv;
            out[k + i] = (float)bi;
            ss[bi] = -3.0e38f;
        }
        __syncthreads();
    }
}

// ---------------------------------------------------------------- launch ----
extern "C" void kernel_launch(void* const* d_in, const int* in_sizes, int n_in,
                              void* d_out, int out_size, void* d_ws, size_t ws_size,
                              hipStream_t stream) {
    const int*   input_ids  = (const int*)d_in[0];
    const int*   attn_mask  = (const int*)d_in[1];
    const int*   query_ids  = (const int*)d_in[2];
    const int*   query_mask = (const int*)d_in[3];
    const float* embed      = (const float*)d_in[4];
    const float* ln_g       = (const float*)d_in[5];
    const float* ln_b       = (const float*)d_in[6];
    const float* kW1        = (const float*)d_in[7];
    const float* kb1        = (const float*)d_in[8];
    const float* kW2        = (const float*)d_in[9];
    const float* kb2        = (const float*)d_in[10];
    const float* qW1        = (const float*)d_in[11];
    const float* qb1        = (const float*)d_in[12];
    const float* qW2        = (const float*)d_in[13];
    const float* qb2        = (const float*)d_in[14];
    const int*   kptr       = (const int*)d_in[15];

    float* ws   = (float*)d_ws;
    float* X    = ws;                            // 257*4096 (row 256 = query)
    float* P1   = X  + (size_t)(BB + 1) * DD;    // 4*256*1024
    float* H1q  = P1 + (size_t)4 * BB * HH;      // 1024
    float* P2   = H1q + HH;                      // 4*256*1024
    float* Qv   = P2 + (size_t)4 * BB * HH;      // 1024
    float* Sc   = Qv + HH;                       // 256

    pool_ln_kernel<<<BB + 1, 1024, 0, stream>>>(input_ids, attn_mask,
                                                query_ids, query_mask,
                                                embed, ln_g, ln_b, X);
    layer1_kernel<<<1280, 256, 0, stream>>>(X, kW1, P1, qW1, qb1, H1q);
    layer2_kernel<<<1280, 256, 0, stream>>>(P1, kb1, kW2, P2, H1q, qW2, qb2, Qv);
    scores_kernel<<<BB, 256, 0, stream>>>(P2, kb2, Qv, Sc);
    topk_kernel<<<1, 256, 0, stream>>>(Sc, kptr, (float*)d_out);
}